// Round 5
// baseline (4918.230 us; speedup 1.0000x reference)
//
#include <hip/hip_runtime.h>
#include <stdint.h>

#define B_DIM 256
#define P_DIM 4096
#define L_DIM 8192
#define NSTEPS 50
#define STEP 0.1f
#define LAM 0.1f

typedef __attribute__((ext_vector_type(8))) short bf16x8;
typedef __attribute__((ext_vector_type(4))) float f32x4;

__device__ __forceinline__ unsigned short f2bf(float f) {
    union { float f; uint32_t u; } x; x.f = f;
    uint32_t r = (x.u + 0x7FFF + ((x.u >> 16) & 1)) >> 16;
    return (unsigned short)r;
}

// ---------------- cast x (f32 -> bf16), vectorized ----------------
__global__ void cast_x_kernel(const float* __restrict__ in, unsigned short* __restrict__ out, int n) {
    int i = (blockIdx.x * blockDim.x + threadIdx.x) * 4;
    if (i < n) {
        float4 v = *(const float4*)&in[i];
        ushort4 o;
        o.x = f2bf(v.x); o.y = f2bf(v.y); o.z = f2bf(v.z); o.w = f2bf(v.w);
        *(ushort4*)&out[i] = o;
    }
}

// ------------- cast + transpose w: w[P][L] f32 -> w_bf[P][L], wT_bf[L][P] -------------
__global__ void cast_transpose_w(const float* __restrict__ w,
                                 unsigned short* __restrict__ w_bf,
                                 unsigned short* __restrict__ wT_bf) {
    __shared__ float tile[32][33];
    int c0 = blockIdx.x * 32;
    int r0 = blockIdx.y * 32;
    int tx = threadIdx.x, ty = threadIdx.y;  // 32 x 8
#pragma unroll
    for (int i = ty; i < 32; i += 8) {
        float v = w[(size_t)(r0 + i) * L_DIM + c0 + tx];
        tile[i][tx] = v;
        w_bf[(size_t)(r0 + i) * L_DIM + c0 + tx] = f2bf(v);
    }
    __syncthreads();
#pragma unroll
    for (int i = ty; i < 32; i += 8) {
        wT_bf[(size_t)(c0 + i) * P_DIM + r0 + tx] = f2bf(tile[tx][i]);
    }
}

// ======================= pipelined NT GEMM (all GEMMs) =======================
// C[MM, NN] = A[MM, KK] @ Bt[NN, KK]^T, bf16 in, f32 accum.
// - T2 XOR-swizzle (both-sides): LDS[row][slot] = global[row][slot ^ (row&7)]
// - T4: NBUF=4, 3-ahead prefetch, counted vmcnt (never 0 until tail), raw s_barrier
// - Wave tiles WM=WN=64 where possible: LDS-read traffic = 2*M*N*K*(1/WM+1/WN)
//   is the binding resource (~65% of 69 TB/s measured r4), so maximize WM*WN.
// MAP 0: XCD panel map (requires MM/BM==4): id%8=XCD, 4 consecutive = one B-panel.
// MAP 1: column-major 2D: by = id % (MM/BM), bx = id / (MM/BM).
// EPI: 0 gram (Cbf = acc - I); 1 b (Cf=acc, u=0.1acc, a=thr);
//      2 iter (u=0.9u+0.1b-0.1acc, a=thr); 3 recon (Cf=acc)
template <int BM, int BN, int BK, int WMC, int WNC, int EPI, int MM, int NN, int KK, int MAP>
__global__ __launch_bounds__(WMC * WNC * 64)
void gemm_pipe(const unsigned short* __restrict__ A,
               const unsigned short* __restrict__ Bt,
               float* __restrict__ Cf, unsigned short* __restrict__ Cbf,
               const float* __restrict__ bvec, float* __restrict__ uvec,
               unsigned short* __restrict__ aout) {
    constexpr int NWAVES = WMC * WNC;
    constexpr int WM = BM / WMC, WN = BN / WNC;
    constexpr int MF = WM / 16, NF = WN / 16;
    constexpr int ACH = BM / (8 * NWAVES);
    constexpr int BCH = BN / (8 * NWAVES);
    constexpr int LPS = ACH + BCH;        // gload_lds per thread per stage
    constexpr int NT = KK / BK;
    static_assert(BK == 64, "swizzle hardcoded for BK=64");
    static_assert(ACH * 8 * NWAVES == BM && BCH * 8 * NWAVES == BN, "stage geometry");
    static_assert(NT % 4 == 0 && NT >= 8, "pipeline geometry");

    __shared__ __align__(16) unsigned short As[4][BM * BK];
    __shared__ __align__(16) unsigned short Bs[4][BN * BK];

    const int tid = threadIdx.x;
    const int w = tid >> 6;
    const int l = tid & 63;
    const int wr = w / WNC, wc = w % WNC;

    const int id = blockIdx.x;
    int bx, by;
    if constexpr (MAP == 0) {
        constexpr int PPX = (NN / BN) / 8;
        static_assert(MM / BM == 4 && (NN / BN) % 8 == 0, "panel map geometry");
        bx = (id & 7) * PPX + ((id >> 3) >> 2);
        by = (id >> 3) & 3;
    } else {
        constexpr int GY = MM / BM;
        by = id % GY;
        bx = id / GY;
    }
    const int row0 = by * BM;
    const int col0 = bx * BN;

    const int lrow = l >> 3;
    const int lcol = (((l & 7) ^ lrow) * 8);   // pre-swizzled source column

    const unsigned short* gA = A + (size_t)(row0 + lrow) * KK + lcol;
    const unsigned short* gB = Bt + (size_t)(col0 + lrow) * KK + lcol;

    auto stage = [&](int buf, int k0) {
#pragma unroll
        for (int i = 0; i < ACH; ++i) {
            const int chunk = i * NWAVES + w;
            __builtin_amdgcn_global_load_lds(
                (const __attribute__((address_space(1))) void*)(gA + (size_t)chunk * 8 * KK + k0),
                (__attribute__((address_space(3))) void*)(&As[buf][chunk * 512]), 16, 0, 0);
        }
#pragma unroll
        for (int i = 0; i < BCH; ++i) {
            const int chunk = i * NWAVES + w;
            __builtin_amdgcn_global_load_lds(
                (const __attribute__((address_space(1))) void*)(gB + (size_t)chunk * 8 * KK + k0),
                (__attribute__((address_space(3))) void*)(&Bs[buf][chunk * 512]), 16, 0, 0);
        }
    };

    f32x4 acc[MF][NF] = {};

    auto compute = [&](int buf) {
#pragma unroll
        for (int kk = 0; kk < BK; kk += 32) {
            const int kslot = (kk >> 3) + (l >> 4);
            bf16x8 af[MF], bfr[NF];
#pragma unroll
            for (int mf = 0; mf < MF; ++mf) {
                const int arow = wr * WM + mf * 16 + (l & 15);
                af[mf] = *(const bf16x8*)&As[buf][arow * BK + ((kslot ^ (arow & 7)) << 3)];
            }
#pragma unroll
            for (int nf = 0; nf < NF; ++nf) {
                const int brow = wc * WN + nf * 16 + (l & 15);
                bfr[nf] = *(const bf16x8*)&Bs[buf][brow * BK + ((kslot ^ (brow & 7)) << 3)];
            }
#pragma unroll
            for (int mf = 0; mf < MF; ++mf)
#pragma unroll
                for (int nf = 0; nf < NF; ++nf)
                    acc[mf][nf] = __builtin_amdgcn_mfma_f32_16x16x32_bf16(
                        af[mf], bfr[nf], acc[mf][nf], 0, 0, 0);
        }
    };

    // phase: wait own stage(t) landed (counted!), barrier (all waves' too), issue t+3, compute t
#define PH(BUF, TT, WAITN, DOSTG)                                            \
    asm volatile("s_waitcnt vmcnt(%0)" ::"i"(WAITN) : "memory");             \
    __builtin_amdgcn_s_barrier();                                            \
    asm volatile("" ::: "memory");                                           \
    if (DOSTG) stage((BUF + 3) & 3, ((TT) + 3) * BK);                        \
    compute(BUF);

    stage(0, 0);
    stage(1, BK);
    stage(2, 2 * BK);
#pragma unroll 1
    for (int t = 0; t < NT - 4; t += 4) {
        PH(0, t + 0, 2 * LPS, true)
        PH(1, t + 1, 2 * LPS, true)
        PH(2, t + 2, 2 * LPS, true)
        PH(3, t + 3, 2 * LPS, true)
    }
    PH(0, NT - 4, 2 * LPS, true)   // stages tile NT-1
    PH(1, NT - 3, 2 * LPS, false)
    PH(2, NT - 2, LPS, false)
    PH(3, NT - 1, 0, false)
#undef PH

    // epilogue: C/D layout col = l&15, row = (l>>4)*4 + j  [m89-verified]
    const int er = (l >> 4) * 4;
    const int ec = l & 15;
#pragma unroll
    for (int mf = 0; mf < MF; ++mf) {
#pragma unroll
        for (int nf = 0; nf < NF; ++nf) {
#pragma unroll
            for (int j = 0; j < 4; ++j) {
                int gr = row0 + wr * WM + mf * 16 + er + j;
                int gc = col0 + wc * WN + nf * 16 + ec;
                size_t idx = (size_t)gr * NN + gc;
                float v = acc[mf][nf][j];
                if constexpr (EPI == 0) {
                    if (gr == gc) v -= 1.0f;
                    Cbf[idx] = f2bf(v);
                } else if constexpr (EPI == 1) {
                    Cf[idx] = v;
                    float u0 = STEP * v;
                    uvec[idx] = u0;
                    float a = (u0 > LAM) ? (u0 - LAM) : 0.0f;
                    aout[idx] = f2bf(a);
                } else if constexpr (EPI == 2) {
                    float un = (1.0f - STEP) * uvec[idx] + STEP * bvec[idx] - STEP * v;
                    uvec[idx] = un;
                    float a = (un > LAM) ? (un - LAM) : 0.0f;
                    aout[idx] = f2bf(a);
                } else {
                    Cf[idx] = v;
                }
            }
        }
    }
}

extern "C" void kernel_launch(void* const* d_in, const int* in_sizes, int n_in,
                              void* d_out, int out_size, void* d_ws, size_t ws_size,
                              hipStream_t stream) {
    (void)in_sizes; (void)n_in; (void)out_size; (void)ws_size;
    const float* x = (const float*)d_in[0];
    const float* w = (const float*)d_in[1];
    float* out = (float*)d_out;

    char* ws = (char*)d_ws;
    unsigned short* wT  = (unsigned short*)ws;                    // [L][P] 64MB
    unsigned short* wbf = wT + (size_t)L_DIM * P_DIM;             // [P][L] 64MB
    unsigned short* G   = wbf + (size_t)P_DIM * L_DIM;            // [L][L] 128MB
    float* bv = (float*)(G + (size_t)L_DIM * L_DIM);              // [B][L] 8MB
    float* uv = bv + (size_t)B_DIM * L_DIM;                       // [B][L] 8MB
    unsigned short* a0 = (unsigned short*)(uv + (size_t)B_DIM * L_DIM);  // 4MB
    unsigned short* a1 = a0 + (size_t)B_DIM * L_DIM;              // 4MB
    unsigned short* xbf = a1 + (size_t)B_DIM * L_DIM;             // 2MB

    // casts
    cast_x_kernel<<<(B_DIM * P_DIM / 4 + 255) / 256, 256, 0, stream>>>(x, xbf, B_DIM * P_DIM);
    cast_transpose_w<<<dim3(L_DIM / 32, P_DIM / 32), dim3(32, 8), 0, stream>>>(w, wbf, wT);

    // gram: G = wT @ wT^T - I. 128x128 tile, 4 waves WM=WN=64, NBUF=4 (128KB LDS),
    // column-major map: one bx's 64 blocks span XCDs -> B-panel hot per XCD L2.
    gemm_pipe<128, 128, 64, 2, 2, 0, L_DIM, L_DIM, P_DIM, 1><<<64 * 64, 256, 0, stream>>>(
        wT, wT, nullptr, G, nullptr, nullptr, nullptr);

    // b = x @ w : 2 waves WM=WN=64, XCD panel map
    gemm_pipe<64, 128, 64, 1, 2, 1, B_DIM, L_DIM, P_DIM, 0><<<256, 128, 0, stream>>>(
        xbf, wT, bv, nullptr, nullptr, uv, a0);

    // 48 scan steps: u = 0.9u + 0.1b - 0.1*(a@G); a' = thr(u)
    unsigned short* ac = a0; unsigned short* an = a1;
    for (int it = 0; it < NSTEPS - 2; ++it) {
        gemm_pipe<64, 128, 64, 1, 2, 2, B_DIM, L_DIM, L_DIM, 0><<<256, 128, 0, stream>>>(
            ac, G, nullptr, nullptr, bv, uv, an);
        unsigned short* t = ac; ac = an; an = t;
    }

    // recon = a_final @ w^T : 2 waves WM=64/WN=32, 256 blocks
    gemm_pipe<64, 64, 64, 1, 2, 3, B_DIM, P_DIM, L_DIM, 0><<<256, 128, 0, stream>>>(
        ac, wbf, out, nullptr, nullptr, nullptr, nullptr);
}

// Round 6
// 2757.496 us; speedup vs baseline: 1.7836x; 1.7836x over previous
//
#include <hip/hip_runtime.h>
#include <stdint.h>

#define B_DIM 256
#define P_DIM 4096
#define L_DIM 8192
#define NSTEPS 50
#define STEP 0.1f
#define LAM 0.1f

typedef __attribute__((ext_vector_type(8))) short bf16x8;
typedef __attribute__((ext_vector_type(4))) float f32x4;

__device__ __forceinline__ unsigned short f2bf(float f) {
    union { float f; uint32_t u; } x; x.f = f;
    uint32_t r = (x.u + 0x7FFF + ((x.u >> 16) & 1)) >> 16;
    return (unsigned short)r;
}
__device__ __forceinline__ float bf2f(unsigned short h) {
    union { uint32_t u; float f; } x; x.u = (uint32_t)h << 16; return x.f;
}

// ---------------- cast x (f32 -> bf16), vectorized ----------------
__global__ void cast_x_kernel(const float* __restrict__ in, unsigned short* __restrict__ out, int n) {
    int i = (blockIdx.x * blockDim.x + threadIdx.x) * 4;
    if (i < n) {
        float4 v = *(const float4*)&in[i];
        ushort4 o;
        o.x = f2bf(v.x); o.y = f2bf(v.y); o.z = f2bf(v.z); o.w = f2bf(v.w);
        *(ushort4*)&out[i] = o;
    }
}

// ------------- cast + transpose w: w[P][L] f32 -> w_bf[P][L], wT_bf[L][P] -------------
__global__ void cast_transpose_w(const float* __restrict__ w,
                                 unsigned short* __restrict__ w_bf,
                                 unsigned short* __restrict__ wT_bf) {
    __shared__ float tile[32][33];
    int c0 = blockIdx.x * 32;
    int r0 = blockIdx.y * 32;
    int tx = threadIdx.x, ty = threadIdx.y;  // 32 x 8
#pragma unroll
    for (int i = ty; i < 32; i += 8) {
        float v = w[(size_t)(r0 + i) * L_DIM + c0 + tx];
        tile[i][tx] = v;
        w_bf[(size_t)(r0 + i) * L_DIM + c0 + tx] = f2bf(v);
    }
    __syncthreads();
#pragma unroll
    for (int i = ty; i < 32; i += 8) {
        wT_bf[(size_t)(c0 + i) * P_DIM + r0 + tx] = f2bf(tile[tx][i]);
    }
}

// ======================= gemm_pipe: NBUF=4 counted-vmcnt (b / recon) =======================
// Round-4-proven structure. C[MM,NN] = A[MM,KK] @ Bt[NN,KK]^T.
template <int BM, int BN, int BK, int WMC, int WNC, int EPI, int MM, int NN, int KK, int MAP>
__global__ __launch_bounds__(WMC * WNC * 64)
void gemm_pipe(const unsigned short* __restrict__ A,
               const unsigned short* __restrict__ Bt,
               float* __restrict__ Cf, unsigned short* __restrict__ Cbf,
               const float* __restrict__ bvec, float* __restrict__ uvec,
               unsigned short* __restrict__ aout) {
    constexpr int NWAVES = WMC * WNC;
    constexpr int WM = BM / WMC, WN = BN / WNC;
    constexpr int MF = WM / 16, NF = WN / 16;
    constexpr int ACH = BM / (8 * NWAVES);
    constexpr int BCH = BN / (8 * NWAVES);
    constexpr int LPS = ACH + BCH;
    constexpr int NT = KK / BK;
    static_assert(BK == 64, "swizzle hardcoded for BK=64");
    static_assert(ACH * 8 * NWAVES == BM && BCH * 8 * NWAVES == BN, "stage geometry");
    static_assert(NT % 4 == 0 && NT >= 8, "pipeline geometry");

    __shared__ __align__(16) unsigned short As[4][BM * BK];
    __shared__ __align__(16) unsigned short Bs[4][BN * BK];

    const int tid = threadIdx.x;
    const int w = tid >> 6;
    const int l = tid & 63;
    const int wr = w / WNC, wc = w % WNC;

    const int id = blockIdx.x;
    int bx, by;
    if constexpr (MAP == 0) {
        constexpr int PPX = (NN / BN) / 8;
        static_assert(MM / BM == 4 && (NN / BN) % 8 == 0, "panel map geometry");
        bx = (id & 7) * PPX + ((id >> 3) >> 2);
        by = (id >> 3) & 3;
    } else {
        constexpr int GY = MM / BM;
        by = id % GY;
        bx = id / GY;
    }
    const int row0 = by * BM;
    const int col0 = bx * BN;

    const int lrow = l >> 3;
    const int lcol = (((l & 7) ^ lrow) * 8);   // pre-swizzled source column

    const unsigned short* gA = A + (size_t)(row0 + lrow) * KK + lcol;
    const unsigned short* gB = Bt + (size_t)(col0 + lrow) * KK + lcol;

    auto stage = [&](int buf, int k0) {
#pragma unroll
        for (int i = 0; i < ACH; ++i) {
            const int chunk = i * NWAVES + w;
            __builtin_amdgcn_global_load_lds(
                (const __attribute__((address_space(1))) void*)(gA + (size_t)chunk * 8 * KK + k0),
                (__attribute__((address_space(3))) void*)(&As[buf][chunk * 512]), 16, 0, 0);
        }
#pragma unroll
        for (int i = 0; i < BCH; ++i) {
            const int chunk = i * NWAVES + w;
            __builtin_amdgcn_global_load_lds(
                (const __attribute__((address_space(1))) void*)(gB + (size_t)chunk * 8 * KK + k0),
                (__attribute__((address_space(3))) void*)(&Bs[buf][chunk * 512]), 16, 0, 0);
        }
    };

    f32x4 acc[MF][NF] = {};

    auto compute = [&](int buf) {
#pragma unroll
        for (int kk = 0; kk < BK; kk += 32) {
            const int kslot = (kk >> 3) + (l >> 4);
            bf16x8 af[MF], bfr[NF];
#pragma unroll
            for (int mf = 0; mf < MF; ++mf) {
                const int arow = wr * WM + mf * 16 + (l & 15);
                af[mf] = *(const bf16x8*)&As[buf][arow * BK + ((kslot ^ (arow & 7)) << 3)];
            }
#pragma unroll
            for (int nf = 0; nf < NF; ++nf) {
                const int brow = wc * WN + nf * 16 + (l & 15);
                bfr[nf] = *(const bf16x8*)&Bs[buf][brow * BK + ((kslot ^ (brow & 7)) << 3)];
            }
#pragma unroll
            for (int mf = 0; mf < MF; ++mf)
#pragma unroll
                for (int nf = 0; nf < NF; ++nf)
                    acc[mf][nf] = __builtin_amdgcn_mfma_f32_16x16x32_bf16(
                        af[mf], bfr[nf], acc[mf][nf], 0, 0, 0);
        }
    };

#define PH(BUF, TT, WAITN, DOSTG)                                            \
    asm volatile("s_waitcnt vmcnt(%0)" ::"i"(WAITN) : "memory");             \
    __builtin_amdgcn_s_barrier();                                            \
    asm volatile("" ::: "memory");                                           \
    if (DOSTG) stage((BUF + 3) & 3, ((TT) + 3) * BK);                        \
    compute(BUF);

    stage(0, 0);
    stage(1, BK);
    stage(2, 2 * BK);
#pragma unroll 1
    for (int t = 0; t < NT - 4; t += 4) {
        PH(0, t + 0, 2 * LPS, true)
        PH(1, t + 1, 2 * LPS, true)
        PH(2, t + 2, 2 * LPS, true)
        PH(3, t + 3, 2 * LPS, true)
    }
    PH(0, NT - 4, 2 * LPS, true)
    PH(1, NT - 3, 2 * LPS, false)
    PH(2, NT - 2, LPS, false)
    PH(3, NT - 1, 0, false)
#undef PH

    const int er = (l >> 4) * 4;
    const int ec = l & 15;
#pragma unroll
    for (int mf = 0; mf < MF; ++mf) {
#pragma unroll
        for (int nf = 0; nf < NF; ++nf) {
#pragma unroll
            for (int j = 0; j < 4; ++j) {
                int gr = row0 + wr * WM + mf * 16 + er + j;
                int gc = col0 + wc * WN + nf * 16 + ec;
                size_t idx = (size_t)gr * NN + gc;
                float v = acc[mf][nf][j];
                if constexpr (EPI == 1) {
                    Cf[idx] = v;
                    float u0 = STEP * v;
                    uvec[idx] = u0;
                    float a = (u0 > LAM) ? (u0 - LAM) : 0.0f;
                    aout[idx] = f2bf(a);
                } else {
                    Cf[idx] = v;
                }
            }
        }
    }
}

// ======================= gemm2: NBUF=2 two-barrier counted-vmcnt (gram / iter split-K) =======
// Big wave tiles (WM*WN maximized) with 8 waves. Phase: wait vmcnt(LPS) [tile t landed],
// barrier, compute(t), barrier, stage(t+2 into same buffer). Loads for t+2 fly during
// phase t+1's compute -> full overlap, never vmcnt(0) until the tail.
// MAP 2: gram 32x32 grid in 4x4 superblocks (L2/L3 reuse). KROW=KLOOP=4096, out = G - I.
// MAP 3: iter split-K: xcd=id&7, tm=(id>>3)&1, pp=id>>4, slice=pp&3, bn=xcd*4+(pp>>2).
//        tm-pair + slices co-located per XCD (G panel fetched once into that L2).
//        KLOOP=2048 at koff=slice*2048; out = bf16 partial [slice][256][8192].
template <int BM, int BN, int WMC, int WNC, int EPI, int KROW, int KLOOP, int MAP>
__global__ __launch_bounds__(WMC * WNC * 64, 2)
void gemm2(const unsigned short* __restrict__ A,
           const unsigned short* __restrict__ Bt,
           unsigned short* __restrict__ Obf) {
    constexpr int NWAVES = WMC * WNC;
    constexpr int WM = BM / WMC, WN = BN / WNC;
    constexpr int MF = WM / 16, NF = WN / 16;
    constexpr int ACH = BM / (8 * NWAVES);
    constexpr int BCH = BN / (8 * NWAVES);
    constexpr int LPS = ACH + BCH;
    constexpr int BK = 64;
    constexpr int NT = KLOOP / BK;
    static_assert(ACH * 8 * NWAVES == BM && BCH * 8 * NWAVES == BN, "stage geometry");
    static_assert(NT % 2 == 0 && NT >= 4, "pipeline geometry");

    __shared__ __align__(16) unsigned short As[2][BM * BK];
    __shared__ __align__(16) unsigned short Bs[2][BN * BK];

    const int tid = threadIdx.x;
    const int w = tid >> 6;
    const int l = tid & 63;
    const int wr = w / WNC, wc = w % WNC;

    const int id = blockIdx.x;
    int bx, by, koff;
    size_t o_off;
    if constexpr (MAP == 2) {
        const int sb = id >> 4, wi = id & 15;
        by = (sb >> 3) * 4 + (wi >> 2);
        bx = (sb & 7) * 4 + (wi & 3);
        koff = 0;
        o_off = 0;
    } else {
        const int xcd = id & 7;
        by = (id >> 3) & 1;                    // tm
        const int pp = id >> 4;
        const int slice = pp & 3;
        bx = xcd * 4 + (pp >> 2);              // bn
        koff = slice * KLOOP;
        o_off = (size_t)slice * B_DIM * L_DIM;
    }
    const int row0 = by * BM;
    const int col0 = bx * BN;

    const int lrow = l >> 3;
    const int lcol = (((l & 7) ^ lrow) * 8);   // pre-swizzled source column

    const unsigned short* gA = A + (size_t)(row0 + lrow) * KROW + koff + lcol;
    const unsigned short* gB = Bt + (size_t)(col0 + lrow) * KROW + koff + lcol;

    auto stage = [&](int buf, int t) {
        const int k0 = t * BK;
#pragma unroll
        for (int i = 0; i < ACH; ++i) {
            const int chunk = i * NWAVES + w;
            __builtin_amdgcn_global_load_lds(
                (const __attribute__((address_space(1))) void*)(gA + (size_t)chunk * 8 * KROW + k0),
                (__attribute__((address_space(3))) void*)(&As[buf][chunk * 512]), 16, 0, 0);
        }
#pragma unroll
        for (int i = 0; i < BCH; ++i) {
            const int chunk = i * NWAVES + w;
            __builtin_amdgcn_global_load_lds(
                (const __attribute__((address_space(1))) void*)(gB + (size_t)chunk * 8 * KROW + k0),
                (__attribute__((address_space(3))) void*)(&Bs[buf][chunk * 512]), 16, 0, 0);
        }
    };

    f32x4 acc[MF][NF] = {};

    auto compute = [&](int buf) {
#pragma unroll
        for (int kk = 0; kk < BK; kk += 32) {
            const int kslot = (kk >> 3) + (l >> 4);
            bf16x8 af[MF], bfr[NF];
#pragma unroll
            for (int mf = 0; mf < MF; ++mf) {
                const int arow = wr * WM + mf * 16 + (l & 15);
                af[mf] = *(const bf16x8*)&As[buf][arow * BK + ((kslot ^ (arow & 7)) << 3)];
            }
#pragma unroll
            for (int nf = 0; nf < NF; ++nf) {
                const int brow = wc * WN + nf * 16 + (l & 15);
                bfr[nf] = *(const bf16x8*)&Bs[buf][brow * BK + ((kslot ^ (brow & 7)) << 3)];
            }
#pragma unroll
            for (int mf = 0; mf < MF; ++mf)
#pragma unroll
                for (int nf = 0; nf < NF; ++nf)
                    acc[mf][nf] = __builtin_amdgcn_mfma_f32_16x16x32_bf16(
                        af[mf], bfr[nf], acc[mf][nf], 0, 0, 0);
        }
    };

    // phase: vmcnt(counted) -> barrier -> compute -> barrier -> stage same buf (t+2)
#define PH2(BUF, WAITN, DOSTG, TT)                                           \
    asm volatile("s_waitcnt vmcnt(%0)" ::"i"(WAITN) : "memory");             \
    __builtin_amdgcn_s_barrier();                                            \
    asm volatile("" ::: "memory");                                           \
    compute(BUF);                                                            \
    __builtin_amdgcn_s_barrier();                                            \
    asm volatile("" ::: "memory");                                           \
    if (DOSTG) stage(BUF, (TT) + 2);

    stage(0, 0);
    stage(1, 1);
#pragma unroll 1
    for (int t = 0; t < NT - 2; t += 2) {
        PH2(0, LPS, true, t)
        PH2(1, LPS, true, t + 1)
    }
    PH2(0, LPS, false, 0)
    PH2(1, 0, false, 0)
#undef PH2

    // epilogue: C/D layout col = l&15, row = (l>>4)*4 + j
    const int er = (l >> 4) * 4;
    const int ec = l & 15;
#pragma unroll
    for (int mf = 0; mf < MF; ++mf) {
#pragma unroll
        for (int nf = 0; nf < NF; ++nf) {
#pragma unroll
            for (int j = 0; j < 4; ++j) {
                int gr = row0 + wr * WM + mf * 16 + er + j;
                int gc = col0 + wc * WN + nf * 16 + ec;
                float v = acc[mf][nf][j];
                if constexpr (EPI == 0) {
                    if (gr == gc) v -= 1.0f;
                    Obf[(size_t)gr * L_DIM + gc] = f2bf(v);
                } else {  // EPI 4: bf16 partial
                    Obf[o_off + (size_t)gr * L_DIM + gc] = f2bf(v);
                }
            }
        }
    }
}

// ---------------- reduce: u' = 0.9u + 0.1b - 0.1*sum(partials); a' = thr(u') ----------------
__global__ void reduce_iter(const unsigned short* __restrict__ P,
                            const float* __restrict__ bv,
                            float* __restrict__ uv,
                            unsigned short* __restrict__ an) {
    constexpr size_t SL = (size_t)B_DIM * L_DIM;
    size_t i = ((size_t)blockIdx.x * 256 + threadIdx.x) * 8;
    float s[8] = {};
#pragma unroll
    for (int sl = 0; sl < 4; ++sl) {
        ushort4 p0 = *(const ushort4*)&P[sl * SL + i];
        ushort4 p1 = *(const ushort4*)&P[sl * SL + i + 4];
        s[0] += bf2f(p0.x); s[1] += bf2f(p0.y); s[2] += bf2f(p0.z); s[3] += bf2f(p0.w);
        s[4] += bf2f(p1.x); s[5] += bf2f(p1.y); s[6] += bf2f(p1.z); s[7] += bf2f(p1.w);
    }
    float4 b0 = *(const float4*)&bv[i];
    float4 b1 = *(const float4*)&bv[i + 4];
    float4 u0 = *(const float4*)&uv[i];
    float4 u1 = *(const float4*)&uv[i + 4];
    float un[8];
    un[0] = 0.9f * u0.x + STEP * b0.x - STEP * s[0];
    un[1] = 0.9f * u0.y + STEP * b0.y - STEP * s[1];
    un[2] = 0.9f * u0.z + STEP * b0.z - STEP * s[2];
    un[3] = 0.9f * u0.w + STEP * b0.w - STEP * s[3];
    un[4] = 0.9f * u1.x + STEP * b1.x - STEP * s[4];
    un[5] = 0.9f * u1.y + STEP * b1.y - STEP * s[5];
    un[6] = 0.9f * u1.z + STEP * b1.z - STEP * s[6];
    un[7] = 0.9f * u1.w + STEP * b1.w - STEP * s[7];
    *(float4*)&uv[i] = make_float4(un[0], un[1], un[2], un[3]);
    *(float4*)&uv[i + 4] = make_float4(un[4], un[5], un[6], un[7]);
    ushort4 a0, a1;
    a0.x = f2bf(un[0] > LAM ? un[0] - LAM : 0.0f);
    a0.y = f2bf(un[1] > LAM ? un[1] - LAM : 0.0f);
    a0.z = f2bf(un[2] > LAM ? un[2] - LAM : 0.0f);
    a0.w = f2bf(un[3] > LAM ? un[3] - LAM : 0.0f);
    a1.x = f2bf(un[4] > LAM ? un[4] - LAM : 0.0f);
    a1.y = f2bf(un[5] > LAM ? un[5] - LAM : 0.0f);
    a1.z = f2bf(un[6] > LAM ? un[6] - LAM : 0.0f);
    a1.w = f2bf(un[7] > LAM ? un[7] - LAM : 0.0f);
    *(ushort4*)&an[i] = a0;
    *(ushort4*)&an[i + 4] = a1;
}

extern "C" void kernel_launch(void* const* d_in, const int* in_sizes, int n_in,
                              void* d_out, int out_size, void* d_ws, size_t ws_size,
                              hipStream_t stream) {
    (void)in_sizes; (void)n_in; (void)out_size; (void)ws_size;
    const float* x = (const float*)d_in[0];
    const float* w = (const float*)d_in[1];
    float* out = (float*)d_out;

    char* ws = (char*)d_ws;
    unsigned short* wT  = (unsigned short*)ws;                    // [L][P] 64MB (dead after b -> reused as partials)
    unsigned short* wbf = wT + (size_t)L_DIM * P_DIM;             // [P][L] 64MB
    unsigned short* G   = wbf + (size_t)P_DIM * L_DIM;            // [L][L] 128MB
    float* bv = (float*)(G + (size_t)L_DIM * L_DIM);              // [B][L] 8MB
    float* uv = bv + (size_t)B_DIM * L_DIM;                       // [B][L] 8MB
    unsigned short* a0 = (unsigned short*)(uv + (size_t)B_DIM * L_DIM);  // 4MB
    unsigned short* a1 = a0 + (size_t)B_DIM * L_DIM;              // 4MB
    unsigned short* xbf = a1 + (size_t)B_DIM * L_DIM;             // 2MB
    unsigned short* Ppart = wT;                                   // [4][B][L] bf16 16MB, overlays wT

    // casts
    cast_x_kernel<<<(B_DIM * P_DIM / 4 + 255) / 256, 256, 0, stream>>>(x, xbf, B_DIM * P_DIM);
    cast_transpose_w<<<dim3(L_DIM / 32, P_DIM / 32), dim3(32, 8), 0, stream>>>(w, wbf, wT);

    // gram: G = wT @ wT^T - I. 256x256 tile, 8 waves WM=128/WN=64, NBUF=2.
    gemm2<256, 256, 2, 4, 0, P_DIM, P_DIM, 2><<<1024, 512, 0, stream>>>(wT, wT, G);

    // b = x @ w : round-4-proven NBUF=4 path (WM=WN=32, 8 waves)
    gemm_pipe<64, 128, 64, 2, 4, 1, B_DIM, L_DIM, P_DIM, 0><<<256, 512, 0, stream>>>(
        xbf, wT, bv, nullptr, nullptr, uv, a0);

    // 48 scan steps: partials = a@G (split-K=4), then reduce applies u-update + threshold
    unsigned short* ac = a0; unsigned short* an = a1;
    for (int it = 0; it < NSTEPS - 2; ++it) {
        gemm2<128, 256, 2, 4, 4, L_DIM, 2048, 3><<<256, 512, 0, stream>>>(ac, G, Ppart);
        reduce_iter<<<(B_DIM * L_DIM) / (256 * 8), 256, 0, stream>>>(Ppart, bv, uv, an);
        unsigned short* t = ac; ac = an; an = t;
    }

    // recon = a_final @ w^T : round-4-proven path
    gemm_pipe<64, 64, 64, 2, 4, 3, B_DIM, P_DIM, L_DIM, 0><<<256, 512, 0, stream>>>(
        ac, wbf, out, nullptr, nullptr, nullptr, nullptr);
}

// Round 7
// 2298.108 us; speedup vs baseline: 2.1401x; 1.1999x over previous
//
#include <hip/hip_runtime.h>
#include <stdint.h>

#define B_DIM 256
#define P_DIM 4096
#define L_DIM 8192
#define NSTEPS 50
#define STEP 0.1f
#define LAM 0.1f
#define FP8_ITERS 40          // scan steps 2..41 in fp8; last 8 in exact bf16 (error-decay tail)
#define GSCALE 64.0f          // G*64 -> sigma ~1 in e4m3 normal range
#define ASCALE 16.0f          // a*16 -> active values out of subnormals
#define INV_SCALE (1.0f / (64.0f * 16.0f))

typedef __attribute__((ext_vector_type(8))) short bf16x8;
typedef __attribute__((ext_vector_type(4))) float f32x4;
typedef __attribute__((ext_vector_type(2))) long lgx2;

__device__ __forceinline__ unsigned short f2bf(float f) {
    union { float f; uint32_t u; } x; x.f = f;
    uint32_t r = (x.u + 0x7FFF + ((x.u >> 16) & 1)) >> 16;
    return (unsigned short)r;
}
__device__ __forceinline__ float bf2f(unsigned short h) {
    union { uint32_t u; float f; } x; x.u = (uint32_t)h << 16; return x.f;
}

// k-shuffled fp8 layout: within each 128-byte K-chunk, 16B slot c holds, for h=c&3:
//   c<4:  k in {h*8..h*8+7}  ++  {32+h*8..32+h*8+7}     (kk pair 0/32)
//   c>=4: k in {64+h*8..}    ++  {96+h*8..}              (kk pair 64/96)
// so lane hi=l>>4 gets BOTH fragments of a kk-pair in ONE ds_read_b128.
// byte position of element k (r = k & 127):
//   dst = (k & ~127) + ((r>>6)&1)*64 + ((r>>3)&3)*16 + ((r>>5)&1)*8 + (k&7)

// ---------------- cast x (f32 -> bf16), vectorized ----------------
__global__ void cast_x_kernel(const float* __restrict__ in, unsigned short* __restrict__ out, int n) {
    int i = (blockIdx.x * blockDim.x + threadIdx.x) * 4;
    if (i < n) {
        float4 v = *(const float4*)&in[i];
        ushort4 o;
        o.x = f2bf(v.x); o.y = f2bf(v.y); o.z = f2bf(v.z); o.w = f2bf(v.w);
        *(ushort4*)&out[i] = o;
    }
}

// ------------- cast + transpose w: w[P][L] f32 -> w_bf[P][L], wT_bf[L][P] -------------
__global__ void cast_transpose_w(const float* __restrict__ w,
                                 unsigned short* __restrict__ w_bf,
                                 unsigned short* __restrict__ wT_bf) {
    __shared__ float tile[32][33];
    int c0 = blockIdx.x * 32;
    int r0 = blockIdx.y * 32;
    int tx = threadIdx.x, ty = threadIdx.y;  // 32 x 8
#pragma unroll
    for (int i = ty; i < 32; i += 8) {
        float v = w[(size_t)(r0 + i) * L_DIM + c0 + tx];
        tile[i][tx] = v;
        w_bf[(size_t)(r0 + i) * L_DIM + c0 + tx] = f2bf(v);
    }
    __syncthreads();
#pragma unroll
    for (int i = ty; i < 32; i += 8) {
        wT_bf[(size_t)(c0 + i) * P_DIM + r0 + tx] = f2bf(tile[tx][i]);
    }
}

// ---------------- quantize G (bf16 -> fp8 e4m3 x64, k-shuffled) ----------------
__global__ void quantize_G(const unsigned short* __restrict__ G, unsigned char* __restrict__ Gf) {
    size_t i = ((size_t)blockIdx.x * 256 + threadIdx.x) * 8;
    bf16x8 v = *(const bf16x8*)&G[i];
    float f[8];
#pragma unroll
    for (int j = 0; j < 8; ++j) f[j] = bf2f((unsigned short)v[j]) * GSCALE;
    int q0 = __builtin_amdgcn_cvt_pk_fp8_f32(f[0], f[1], 0, false);
    q0 = __builtin_amdgcn_cvt_pk_fp8_f32(f[2], f[3], q0, true);
    int q1 = __builtin_amdgcn_cvt_pk_fp8_f32(f[4], f[5], 0, false);
    q1 = __builtin_amdgcn_cvt_pk_fp8_f32(f[6], f[7], q1, true);
    const int r = (int)(i & 127);
    size_t dst = (i & ~(size_t)127) + (size_t)((((r >> 6) & 1) << 6) + (((r >> 3) & 3) << 4) + (((r >> 5) & 1) << 3));
    *(int2*)(Gf + dst) = make_int2(q0, q1);
}

// ======================= gemm_pipe: NBUF=4 counted-vmcnt (b / recon) =======================
template <int BM, int BN, int BK, int WMC, int WNC, int EPI, int MM, int NN, int KK, int MAP>
__global__ __launch_bounds__(WMC * WNC * 64)
void gemm_pipe(const unsigned short* __restrict__ A,
               const unsigned short* __restrict__ Bt,
               float* __restrict__ Cf,
               float* __restrict__ uvec,
               unsigned short* __restrict__ aout,
               unsigned char* __restrict__ afp8) {
    constexpr int NWAVES = WMC * WNC;
    constexpr int WM = BM / WMC, WN = BN / WNC;
    constexpr int MF = WM / 16, NF = WN / 16;
    constexpr int ACH = BM / (8 * NWAVES);
    constexpr int BCH = BN / (8 * NWAVES);
    constexpr int LPS = ACH + BCH;
    constexpr int NT = KK / BK;
    static_assert(BK == 64, "swizzle hardcoded for BK=64");
    static_assert(ACH * 8 * NWAVES == BM && BCH * 8 * NWAVES == BN, "stage geometry");
    static_assert(NT % 4 == 0 && NT >= 8, "pipeline geometry");

    __shared__ __align__(16) unsigned short As[4][BM * BK];
    __shared__ __align__(16) unsigned short Bs[4][BN * BK];

    const int tid = threadIdx.x;
    const int w = tid >> 6;
    const int l = tid & 63;
    const int wr = w / WNC, wc = w % WNC;

    const int id = blockIdx.x;
    int bx, by;
    if constexpr (MAP == 0) {
        constexpr int PPX = (NN / BN) / 8;
        static_assert(MM / BM == 4 && (NN / BN) % 8 == 0, "panel map geometry");
        bx = (id & 7) * PPX + ((id >> 3) >> 2);
        by = (id >> 3) & 3;
    } else {
        constexpr int GY = MM / BM;
        by = id % GY;
        bx = id / GY;
    }
    const int row0 = by * BM;
    const int col0 = bx * BN;

    const int lrow = l >> 3;
    const int lcol = (((l & 7) ^ lrow) * 8);

    const unsigned short* gA = A + (size_t)(row0 + lrow) * KK + lcol;
    const unsigned short* gB = Bt + (size_t)(col0 + lrow) * KK + lcol;

    auto stage = [&](int buf, int k0) {
#pragma unroll
        for (int i = 0; i < ACH; ++i) {
            const int chunk = i * NWAVES + w;
            __builtin_amdgcn_global_load_lds(
                (const __attribute__((address_space(1))) void*)(gA + (size_t)chunk * 8 * KK + k0),
                (__attribute__((address_space(3))) void*)(&As[buf][chunk * 512]), 16, 0, 0);
        }
#pragma unroll
        for (int i = 0; i < BCH; ++i) {
            const int chunk = i * NWAVES + w;
            __builtin_amdgcn_global_load_lds(
                (const __attribute__((address_space(1))) void*)(gB + (size_t)chunk * 8 * KK + k0),
                (__attribute__((address_space(3))) void*)(&Bs[buf][chunk * 512]), 16, 0, 0);
        }
    };

    f32x4 acc[MF][NF] = {};

    auto compute = [&](int buf) {
#pragma unroll
        for (int kk = 0; kk < BK; kk += 32) {
            const int kslot = (kk >> 3) + (l >> 4);
            bf16x8 af[MF], bfr[NF];
#pragma unroll
            for (int mf = 0; mf < MF; ++mf) {
                const int arow = wr * WM + mf * 16 + (l & 15);
                af[mf] = *(const bf16x8*)&As[buf][arow * BK + ((kslot ^ (arow & 7)) << 3)];
            }
#pragma unroll
            for (int nf = 0; nf < NF; ++nf) {
                const int brow = wc * WN + nf * 16 + (l & 15);
                bfr[nf] = *(const bf16x8*)&Bs[buf][brow * BK + ((kslot ^ (brow & 7)) << 3)];
            }
#pragma unroll
            for (int mf = 0; mf < MF; ++mf)
#pragma unroll
                for (int nf = 0; nf < NF; ++nf)
                    acc[mf][nf] = __builtin_amdgcn_mfma_f32_16x16x32_bf16(
                        af[mf], bfr[nf], acc[mf][nf], 0, 0, 0);
        }
    };

#define PH(BUF, TT, WAITN, DOSTG)                                            \
    asm volatile("s_waitcnt vmcnt(%0)" ::"i"(WAITN) : "memory");             \
    __builtin_amdgcn_s_barrier();                                            \
    asm volatile("" ::: "memory");                                           \
    if (DOSTG) stage((BUF + 3) & 3, ((TT) + 3) * BK);                        \
    compute(BUF);

    stage(0, 0);
    stage(1, BK);
    stage(2, 2 * BK);
#pragma unroll 1
    for (int t = 0; t < NT - 4; t += 4) {
        PH(0, t + 0, 2 * LPS, true)
        PH(1, t + 1, 2 * LPS, true)
        PH(2, t + 2, 2 * LPS, true)
        PH(3, t + 3, 2 * LPS, true)
    }
    PH(0, NT - 4, 2 * LPS, true)
    PH(1, NT - 3, 2 * LPS, false)
    PH(2, NT - 2, LPS, false)
    PH(3, NT - 1, 0, false)
#undef PH

    const int er = (l >> 4) * 4;
    const int ec = l & 15;
#pragma unroll
    for (int mf = 0; mf < MF; ++mf) {
#pragma unroll
        for (int nf = 0; nf < NF; ++nf) {
#pragma unroll
            for (int j = 0; j < 4; ++j) {
                int gr = row0 + wr * WM + mf * 16 + er + j;
                int gc = col0 + wc * WN + nf * 16 + ec;
                size_t idx = (size_t)gr * NN + gc;
                float v = acc[mf][nf][j];
                if constexpr (EPI == 1) {
                    Cf[idx] = v;
                    float u0 = STEP * v;
                    uvec[idx] = u0;
                    float a = (u0 > LAM) ? (u0 - LAM) : 0.0f;
                    aout[idx] = f2bf(a);
                    // fp8 a (x16), k-shuffled
                    float a16 = a * ASCALE;
                    int q = __builtin_amdgcn_cvt_pk_fp8_f32(a16, a16, 0, false);
                    const int r = gc & 127;
                    size_t fd = (size_t)gr * L_DIM + (size_t)(gc & ~127) +
                                (size_t)((((r >> 6) & 1) << 6) + (((r >> 3) & 3) << 4) + (((r >> 5) & 1) << 3) + (r & 7));
                    afp8[fd] = (unsigned char)(q & 0xff);
                } else {
                    Cf[idx] = v;
                }
            }
        }
    }
}

// ======================= gemm2: bf16 NBUF=2 two-barrier counted-vmcnt (gram / bf16-tail iters) =====
template <int BM, int BN, int WMC, int WNC, int EPI, int KROW, int KLOOP, int MAP>
__global__ __launch_bounds__(WMC * WNC * 64, 2)
void gemm2(const unsigned short* __restrict__ A,
           const unsigned short* __restrict__ Bt,
           unsigned short* __restrict__ Obf) {
    constexpr int NWAVES = WMC * WNC;
    constexpr int WM = BM / WMC, WN = BN / WNC;
    constexpr int MF = WM / 16, NF = WN / 16;
    constexpr int ACH = BM / (8 * NWAVES);
    constexpr int BCH = BN / (8 * NWAVES);
    constexpr int LPS = ACH + BCH;
    constexpr int BK = 64;
    constexpr int NT = KLOOP / BK;
    static_assert(ACH * 8 * NWAVES == BM && BCH * 8 * NWAVES == BN, "stage geometry");
    static_assert(NT % 2 == 0 && NT >= 4, "pipeline geometry");

    __shared__ __align__(16) unsigned short As[2][BM * BK];
    __shared__ __align__(16) unsigned short Bs[2][BN * BK];

    const int tid = threadIdx.x;
    const int w = tid >> 6;
    const int l = tid & 63;
    const int wr = w / WNC, wc = w % WNC;

    const int id = blockIdx.x;
    int bx, by, koff;
    size_t o_off;
    if constexpr (MAP == 2) {
        const int sb = id >> 4, wi = id & 15;
        by = (sb >> 3) * 4 + (wi >> 2);
        bx = (sb & 7) * 4 + (wi & 3);
        koff = 0;
        o_off = 0;
    } else {
        const int xcd = id & 7;
        by = (id >> 3) & 1;
        const int pp = id >> 4;
        const int slice = pp & 3;
        bx = xcd * 4 + (pp >> 2);
        koff = slice * KLOOP;
        o_off = (size_t)slice * B_DIM * L_DIM;
    }
    const int row0 = by * BM;
    const int col0 = bx * BN;

    const int lrow = l >> 3;
    const int lcol = (((l & 7) ^ lrow) * 8);

    const unsigned short* gA = A + (size_t)(row0 + lrow) * KROW + koff + lcol;
    const unsigned short* gB = Bt + (size_t)(col0 + lrow) * KROW + koff + lcol;

    auto stage = [&](int buf, int t) {
        const int k0 = t * BK;
#pragma unroll
        for (int i = 0; i < ACH; ++i) {
            const int chunk = i * NWAVES + w;
            __builtin_amdgcn_global_load_lds(
                (const __attribute__((address_space(1))) void*)(gA + (size_t)chunk * 8 * KROW + k0),
                (__attribute__((address_space(3))) void*)(&As[buf][chunk * 512]), 16, 0, 0);
        }
#pragma unroll
        for (int i = 0; i < BCH; ++i) {
            const int chunk = i * NWAVES + w;
            __builtin_amdgcn_global_load_lds(
                (const __attribute__((address_space(1))) void*)(gB + (size_t)chunk * 8 * KROW + k0),
                (__attribute__((address_space(3))) void*)(&Bs[buf][chunk * 512]), 16, 0, 0);
        }
    };

    f32x4 acc[MF][NF] = {};

    auto compute = [&](int buf) {
#pragma unroll
        for (int kk = 0; kk < BK; kk += 32) {
            const int kslot = (kk >> 3) + (l >> 4);
            bf16x8 af[MF], bfr[NF];
#pragma unroll
            for (int mf = 0; mf < MF; ++mf) {
                const int arow = wr * WM + mf * 16 + (l & 15);
                af[mf] = *(const bf16x8*)&As[buf][arow * BK + ((kslot ^ (arow & 7)) << 3)];
            }
#pragma unroll
            for (int nf = 0; nf < NF; ++nf) {
                const int brow = wc * WN + nf * 16 + (l & 15);
                bfr[nf] = *(const bf16x8*)&Bs[buf][brow * BK + ((kslot ^ (brow & 7)) << 3)];
            }
#pragma unroll
            for (int mf = 0; mf < MF; ++mf)
#pragma unroll
                for (int nf = 0; nf < NF; ++nf)
                    acc[mf][nf] = __builtin_amdgcn_mfma_f32_16x16x32_bf16(
                        af[mf], bfr[nf], acc[mf][nf], 0, 0, 0);
        }
    };

#define PH2(BUF, WAITN, DOSTG, TT)                                           \
    asm volatile("s_waitcnt vmcnt(%0)" ::"i"(WAITN) : "memory");             \
    __builtin_amdgcn_s_barrier();                                            \
    asm volatile("" ::: "memory");                                           \
    compute(BUF);                                                            \
    __builtin_amdgcn_s_barrier();                                            \
    asm volatile("" ::: "memory");                                           \
    if (DOSTG) stage(BUF, (TT) + 2);

    stage(0, 0);
    stage(1, 1);
#pragma unroll 1
    for (int t = 0; t < NT - 2; t += 2) {
        PH2(0, LPS, true, t)
        PH2(1, LPS, true, t + 1)
    }
    PH2(0, LPS, false, 0)
    PH2(1, 0, false, 0)
#undef PH2

    const int er = (l >> 4) * 4;
    const int ec = l & 15;
#pragma unroll
    for (int mf = 0; mf < MF; ++mf) {
#pragma unroll
        for (int nf = 0; nf < NF; ++nf) {
#pragma unroll
            for (int j = 0; j < 4; ++j) {
                int gr = row0 + wr * WM + mf * 16 + er + j;
                int gc = col0 + wc * WN + nf * 16 + ec;
                float v = acc[mf][nf][j];
                if constexpr (EPI == 0) {
                    if (gr == gc) v -= 1.0f;
                    Obf[(size_t)gr * L_DIM + gc] = f2bf(v);
                } else {
                    Obf[o_off + (size_t)gr * L_DIM + gc] = f2bf(v);
                }
            }
        }
    }
}

// ======================= gemm_fp8: iter GEMM, fp8 e4m3, BK=128B, NBUF=2 =======================
// A [B][L] fp8 (a*16, k-shuffled), Bt [L][L] fp8 (G*64, k-shuffled).
// One ds_read_b128 per fragment-PAIR (kk and kk+32) -> LDS instr count halved vs bf16.
// Split-K=4 XCD map as bf16 MAP 3. Output: bf16 partials * 1/1024.
template <int BM, int BN, int WMC, int WNC>
__global__ __launch_bounds__(WMC * WNC * 64, 2)
void gemm_fp8(const unsigned char* __restrict__ A,
              const unsigned char* __restrict__ Bt,
              unsigned short* __restrict__ Obf) {
    constexpr int NWAVES = WMC * WNC;              // 8
    constexpr int WM = BM / WMC, WN = BN / WNC;    // 64, 64
    constexpr int MF = WM / 16, NF = WN / 16;      // 4, 4
    constexpr int BKB = 128;                       // K bytes (=elems) per tile
    constexpr int ACH = BM / (8 * NWAVES);         // 2
    constexpr int BCH = BN / (8 * NWAVES);         // 4
    constexpr int LPS = ACH + BCH;                 // 6
    constexpr int KLOOP = 2048;                    // K elems per slice
    constexpr int NT = KLOOP / BKB;                // 16
    constexpr int KKB = L_DIM;                     // row stride in bytes
    static_assert(ACH * 8 * NWAVES == BM && BCH * 8 * NWAVES == BN, "stage geometry");

    __shared__ __align__(16) unsigned char As[2][BM * BKB];   // 32 KB
    __shared__ __align__(16) unsigned char Bs[2][BN * BKB];   // 64 KB

    const int tid = threadIdx.x;
    const int w = tid >> 6;
    const int l = tid & 63;
    const int wr = w / WNC, wc = w % WNC;

    const int id = blockIdx.x;
    const int xcd = id & 7;
    const int by = (id >> 3) & 1;
    const int pp = id >> 4;
    const int slice = pp & 3;
    const int bx = xcd * 4 + (pp >> 2);
    const int row0 = by * BM;
    const int col0 = bx * BN;
    const int koff = slice * KLOOP;

    const int lrow = l >> 3;
    const int lcol = (((l & 7) ^ lrow) << 4);   // pre-swizzled source byte offset

    const unsigned char* gA = A + (size_t)(row0 + lrow) * KKB + koff + lcol;
    const unsigned char* gB = Bt + (size_t)(col0 + lrow) * KKB + koff + lcol;

    auto stage = [&](int buf, int t) {
        const int k0 = t * BKB;
#pragma unroll
        for (int i = 0; i < ACH; ++i) {
            const int chunk = i * NWAVES + w;
            __builtin_amdgcn_global_load_lds(
                (const __attribute__((address_space(1))) void*)(gA + (size_t)chunk * 8 * KKB + k0),
                (__attribute__((address_space(3))) void*)(&As[buf][chunk * 1024]), 16, 0, 0);
        }
#pragma unroll
        for (int i = 0; i < BCH; ++i) {
            const int chunk = i * NWAVES + w;
            __builtin_amdgcn_global_load_lds(
                (const __attribute__((address_space(1))) void*)(gB + (size_t)chunk * 8 * KKB + k0),
                (__attribute__((address_space(3))) void*)(&Bs[buf][chunk * 1024]), 16, 0, 0);
        }
    };

    f32x4 acc[MF][NF] = {};

    auto compute = [&](int buf) {
#pragma unroll
        for (int kp = 0; kp < 2; ++kp) {           // kk-pairs: (0,32) and (64,96)
            const int c = kp * 4 + (l >> 4);       // content slot
            lgx2 af[MF], bfr[NF];
#pragma unroll
            for (int mf = 0; mf < MF; ++mf) {
                const int arow = wr * WM + mf * 16 + (l & 15);
                af[mf] = *(const lgx2*)&As[buf][arow * BKB + ((c ^ (arow & 7)) << 4)];
            }
#pragma unroll
            for (int nf = 0; nf < NF; ++nf) {
                const int brow = wc * WN + nf * 16 + (l & 15);
                bfr[nf] = *(const lgx2*)&Bs[buf][brow * BKB + ((c ^ (brow & 7)) << 4)];
            }
#pragma unroll
            for (int mf = 0; mf < MF; ++mf)
#pragma unroll
                for (int nf = 0; nf < NF; ++nf) {
                    acc[mf][nf] = __builtin_amdgcn_mfma_f32_16x16x32_fp8_fp8(
                        af[mf][0], bfr[nf][0], acc[mf][nf], 0, 0, 0);
                    acc[mf][nf] = __builtin_amdgcn_mfma_f32_16x16x32_fp8_fp8(
                        af[mf][1], bfr[nf][1], acc[mf][nf], 0, 0, 0);
                }
        }
    };

#define PH2(BUF, WAITN, DOSTG, TT)                                           \
    asm volatile("s_waitcnt vmcnt(%0)" ::"i"(WAITN) : "memory");             \
    __builtin_amdgcn_s_barrier();                                            \
    asm volatile("" ::: "memory");                                           \
    compute(BUF);                                                            \
    __builtin_amdgcn_s_barrier();                                            \
    asm volatile("" ::: "memory");                                           \
    if (DOSTG) stage(BUF, (TT) + 2);

    stage(0, 0);
    stage(1, 1);
#pragma unroll 1
    for (int t = 0; t < NT - 2; t += 2) {
        PH2(0, LPS, true, t)
        PH2(1, LPS, true, t + 1)
    }
    PH2(0, LPS, false, 0)
    PH2(1, 0, false, 0)
#undef PH2

    const int er = (l >> 4) * 4;
    const int ec = l & 15;
    const size_t o_off = (size_t)slice * B_DIM * L_DIM;
#pragma unroll
    for (int mf = 0; mf < MF; ++mf)
#pragma unroll
        for (int nf = 0; nf < NF; ++nf)
#pragma unroll
            for (int j = 0; j < 4; ++j) {
                int gr = row0 + wr * WM + mf * 16 + er + j;
                int gc = col0 + wc * WN + nf * 16 + ec;
                Obf[o_off + (size_t)gr * L_DIM + gc] = f2bf(acc[mf][nf][j] * INV_SCALE);
            }
}

// ---------------- reduce: u' = 0.9u + 0.1b - 0.1*sum(partials); a' = thr(u') (bf16 + fp8) ------
__global__ void reduce_iter(const unsigned short* __restrict__ P,
                            const float* __restrict__ bv,
                            float* __restrict__ uv,
                            unsigned short* __restrict__ an,
                            unsigned char* __restrict__ anf) {
    constexpr size_t SL = (size_t)B_DIM * L_DIM;
    size_t i = ((size_t)blockIdx.x * 256 + threadIdx.x) * 8;
    float s[8] = {};
#pragma unroll
    for (int sl = 0; sl < 4; ++sl) {
        ushort4 p0 = *(const ushort4*)&P[sl * SL + i];
        ushort4 p1 = *(const ushort4*)&P[sl * SL + i + 4];
        s[0] += bf2f(p0.x); s[1] += bf2f(p0.y); s[2] += bf2f(p0.z); s[3] += bf2f(p0.w);
        s[4] += bf2f(p1.x); s[5] += bf2f(p1.y); s[6] += bf2f(p1.z); s[7] += bf2f(p1.w);
    }
    float4 b0 = *(const float4*)&bv[i];
    float4 b1 = *(const float4*)&bv[i + 4];
    float4 u0 = *(const float4*)&uv[i];
    float4 u1 = *(const float4*)&uv[i + 4];
    float un[8];
    un[0] = 0.9f * u0.x + STEP * b0.x - STEP * s[0];
    un[1] = 0.9f * u0.y + STEP * b0.y - STEP * s[1];
    un[2] = 0.9f * u0.z + STEP * b0.z - STEP * s[2];
    un[3] = 0.9f * u0.w + STEP * b0.w - STEP * s[3];
    un[4] = 0.9f * u1.x + STEP * b1.x - STEP * s[4];
    un[5] = 0.9f * u1.y + STEP * b1.y - STEP * s[5];
    un[6] = 0.9f * u1.z + STEP * b1.z - STEP * s[6];
    un[7] = 0.9f * u1.w + STEP * b1.w - STEP * s[7];
    *(float4*)&uv[i] = make_float4(un[0], un[1], un[2], un[3]);
    *(float4*)&uv[i + 4] = make_float4(un[4], un[5], un[6], un[7]);
    float a[8];
#pragma unroll
    for (int j = 0; j < 8; ++j) a[j] = (un[j] > LAM) ? (un[j] - LAM) : 0.0f;
    ushort4 o0, o1;
    o0.x = f2bf(a[0]); o0.y = f2bf(a[1]); o0.z = f2bf(a[2]); o0.w = f2bf(a[3]);
    o1.x = f2bf(a[4]); o1.y = f2bf(a[5]); o1.z = f2bf(a[6]); o1.w = f2bf(a[7]);
    *(ushort4*)&an[i] = o0;
    *(ushort4*)&an[i + 4] = o1;
    // fp8 a (x16), k-shuffled within 128-elem chunks
    int q0 = __builtin_amdgcn_cvt_pk_fp8_f32(a[0] * ASCALE, a[1] * ASCALE, 0, false);
    q0 = __builtin_amdgcn_cvt_pk_fp8_f32(a[2] * ASCALE, a[3] * ASCALE, q0, true);
    int q1 = __builtin_amdgcn_cvt_pk_fp8_f32(a[4] * ASCALE, a[5] * ASCALE, 0, false);
    q1 = __builtin_amdgcn_cvt_pk_fp8_f32(a[6] * ASCALE, a[7] * ASCALE, q1, true);
    const int r = (int)(i & 127);
    size_t dst = (i & ~(size_t)127) + (size_t)((((r >> 6) & 1) << 6) + (((r >> 3) & 3) << 4) + (((r >> 5) & 1) << 3));
    *(int2*)(anf + dst) = make_int2(q0, q1);
}

extern "C" void kernel_launch(void* const* d_in, const int* in_sizes, int n_in,
                              void* d_out, int out_size, void* d_ws, size_t ws_size,
                              hipStream_t stream) {
    (void)in_sizes; (void)n_in; (void)out_size; (void)ws_size;
    const float* x = (const float*)d_in[0];
    const float* w = (const float*)d_in[1];
    float* out = (float*)d_out;

    char* ws = (char*)d_ws;
    unsigned short* wT  = (unsigned short*)ws;                    // [L][P] 64MB; dead after b -> G_fp8
    unsigned char*  Gf  = (unsigned char*)ws;                     // [L][L] fp8 64MB (overlays wT)
    unsigned short* wbf = wT + (size_t)L_DIM * P_DIM;             // [P][L] 64MB
    unsigned short* G   = wbf + (size_t)P_DIM * L_DIM;            // [L][L] bf16 128MB
    float* bv = (float*)(G + (size_t)L_DIM * L_DIM);              // [B][L] 8MB
    float* uv = bv + (size_t)B_DIM * L_DIM;                       // [B][L] 8MB
    unsigned short* a0 = (unsigned short*)(uv + (size_t)B_DIM * L_DIM);  // 4MB
    unsigned short* a1 = a0 + (size_t)B_DIM * L_DIM;              // 4MB
    unsigned short* xbf = a1 + (size_t)B_DIM * L_DIM;             // 2MB
    unsigned char* a0f = (unsigned char*)(xbf + (size_t)B_DIM * P_DIM); // 2MB
    unsigned char* a1f = a0f + (size_t)B_DIM * L_DIM;             // 2MB
    unsigned short* Ppart = (unsigned short*)(a1f + (size_t)B_DIM * L_DIM); // [4][B][L] bf16 16MB

    // casts
    cast_x_kernel<<<(B_DIM * P_DIM / 4 + 255) / 256, 256, 0, stream>>>(x, xbf, B_DIM * P_DIM);
    cast_transpose_w<<<dim3(L_DIM / 32, P_DIM / 32), dim3(32, 8), 0, stream>>>(w, wbf, wT);

    // gram: G = wT @ wT^T - I (bf16, r6 structure)
    gemm2<256, 256, 2, 4, 0, P_DIM, P_DIM, 2><<<1024, 512, 0, stream>>>(wT, wT, G);

    // b = x @ w (needs wT; writes bv, uv, a0 bf16, a0f fp8)
    gemm_pipe<64, 128, 64, 2, 4, 1, B_DIM, L_DIM, P_DIM, 0><<<256, 512, 0, stream>>>(
        xbf, wT, bv, uv, a0, a0f);

    // quantize G -> fp8 (x64), k-shuffled; overlays wT (dead now)
    quantize_G<<<(int)(((size_t)L_DIM * L_DIM / 8) / 256), 256, 0, stream>>>(G, Gf);

    // scan steps: 40 in fp8, last 8 in exact bf16 (fp8 fixed-point error decays through tail)
    unsigned short* ac = a0; unsigned short* an = a1;
    unsigned char* acf = a0f; unsigned char* anf = a1f;
    for (int it = 0; it < FP8_ITERS; ++it) {
        gemm_fp8<128, 256, 2, 4><<<256, 512, 0, stream>>>(acf, Gf, Ppart);
        reduce_iter<<<(B_DIM * L_DIM) / (256 * 8), 256, 0, stream>>>(Ppart, bv, uv, an, anf);
        unsigned short* t = ac; ac = an; an = t;
        unsigned char* tf = acf; acf = anf; anf = tf;
    }
    for (int it = 0; it < (NSTEPS - 2) - FP8_ITERS; ++it) {
        gemm2<128, 256, 2, 4, 4, L_DIM, 2048, 3><<<256, 512, 0, stream>>>(ac, G, Ppart);
        reduce_iter<<<(B_DIM * L_DIM) / (256 * 8), 256, 0, stream>>>(Ppart, bv, uv, an, anf);
        unsigned short* t = ac; ac = an; an = t;
        unsigned char* tf = acf; acf = anf; anf = tf;
    }

    // recon = a_final @ w^T
    gemm_pipe<64, 64, 64, 2, 4, 3, B_DIM, P_DIM, L_DIM, 0><<<256, 512, 0, stream>>>(
        ac, wbf, out, nullptr, nullptr, nullptr);
}